// Round 1
// baseline (177.284 us; speedup 1.0000x reference)
//
#include <hip/hip_runtime.h>
#include <hip/hip_bf16.h>

#define Bdim 512
#define Sdim 50
#define Hdim 512
#define Ndim 20000
#define Kdim2 1024   // 2*H
#define SEENW 640    // u32 words per row for the seen-bitmask (20000 bits -> 625, pad 640)

typedef __bf16 bf16x8 __attribute__((ext_vector_type(8)));
typedef float f32x4 __attribute__((ext_vector_type(4)));
typedef unsigned short u16;

__device__ __forceinline__ u16 f2bf(float f) {
  unsigned u = __builtin_bit_cast(unsigned, f);
  u = (u + 0x7fffu + ((u >> 16) & 1u)) >> 16;   // RNE
  return (u16)u;
}

// ---------------- casts ----------------
__global__ __launch_bounds__(256) void cast_kernel(const float* __restrict__ src,
                                                   u16* __restrict__ dst, int n4) {
  int stride = gridDim.x * blockDim.x;
  for (int i = blockIdx.x * blockDim.x + threadIdx.x; i < n4; i += stride) {
    float4 v = reinterpret_cast<const float4*>(src)[i];
    ushort4 o;
    o.x = f2bf(v.x); o.y = f2bf(v.y); o.z = f2bf(v.z); o.w = f2bf(v.w);
    reinterpret_cast<ushort4*>(dst)[i] = o;
  }
}

__global__ __launch_bounds__(256) void cast3_kernel(const float* __restrict__ a, u16* __restrict__ da,
                                                    const float* __restrict__ b, u16* __restrict__ db,
                                                    const float* __restrict__ c, u16* __restrict__ dc) {
  int i = blockIdx.x * blockDim.x + threadIdx.x;   // 65536 threads, one float4 each
  float4 v; ushort4 o;
  v = reinterpret_cast<const float4*>(a)[i];
  o.x = f2bf(v.x); o.y = f2bf(v.y); o.z = f2bf(v.z); o.w = f2bf(v.w);
  reinterpret_cast<ushort4*>(da)[i] = o;
  v = reinterpret_cast<const float4*>(b)[i];
  o.x = f2bf(v.x); o.y = f2bf(v.y); o.z = f2bf(v.z); o.w = f2bf(v.w);
  reinterpret_cast<ushort4*>(db)[i] = o;
  v = reinterpret_cast<const float4*>(c)[i];
  o.x = f2bf(v.x); o.y = f2bf(v.y); o.z = f2bf(v.z); o.w = f2bf(v.w);
  reinterpret_cast<ushort4*>(dc)[i] = o;
}

// ---------------- init (scores=V_b, lm=0, seen=0) ----------------
__global__ __launch_bounds__(256) void init_kernel(float* __restrict__ scores,
                                                   float* __restrict__ lm,
                                                   unsigned* __restrict__ seen,
                                                   const float* __restrict__ Vb) {
  int stride = gridDim.x * blockDim.x;
  int t = blockIdx.x * blockDim.x + threadIdx.x;
  float vb = Vb[0];
  for (int i = t; i < Bdim * Sdim; i += stride) scores[i] = vb;
  for (int i = t; i < Bdim * Hdim; i += stride) lm[i] = 0.f;
  for (int i = t; i < Bdim * SEENW; i += stride) seen[i] = 0u;
}

// ---------------- seen-item scatter ----------------
__global__ __launch_bounds__(256) void scatter_kernel(const int* __restrict__ iseq,
                                                      unsigned* __restrict__ seen) {
  int i = blockIdx.x * blockDim.x + threadIdx.x;
  if (i < Bdim * Sdim) {
    int b = i / Sdim;
    int it = iseq[i];
    if (it > 0) atomicOr(&seen[b * SEENW + (it >> 5)], 1u << (it & 31));
  }
}

// ---------------- softmax over S + context readout -> feat (bf16) ----------------
__global__ __launch_bounds__(256) void softmax_ctx_kernel(
    const float* __restrict__ scores, const unsigned char* __restrict__ mask,
    const float* __restrict__ all_memory, const float* __restrict__ last_memory,
    u16* __restrict__ feat) {
  int b = blockIdx.x;
  __shared__ float alpha[Sdim];
  int tid = threadIdx.x;
  if (tid < 64) {
    float s = -1e30f;
    if (tid < Sdim) {
      s = scores[b * Sdim + tid];
      if (mask[b * Sdim + tid]) s = -1e9f;   // mask is all-false in this problem
    }
    float m = s;
#pragma unroll
    for (int off = 32; off; off >>= 1) m = fmaxf(m, __shfl_xor(m, off));
    float e = (tid < Sdim) ? __expf(s - m) : 0.f;
    float sum = e;
#pragma unroll
    for (int off = 32; off; off >>= 1) sum += __shfl_xor(sum, off);
    if (tid < Sdim) alpha[tid] = e / sum;
  }
  __syncthreads();
  for (int h = tid; h < Hdim; h += 256) {
    const float* amp = all_memory + ((long)b * Sdim) * Hdim + h;
    float c = 0.f;
#pragma unroll 5
    for (int s = 0; s < Sdim; ++s) c += alpha[s] * amp[(long)s * Hdim];
    feat[b * Kdim2 + h] = f2bf(c);
    feat[b * Kdim2 + Hdim + h] = f2bf(last_memory[b * Hdim + h]);
  }
}

// ---------------- MFMA GEMM, B-transposed layout (A: MxK, Bmat: NxK, both bf16) ----
// EPI 0: atomicAdd f32 into out (M x N), supports split-K via gridDim.z
// EPI 1: scores[r] += sum_c V[c]*tanh(acc + lm[b,c])   (additive-attention scores)
// EPI 2: out[r*Ndim+c] = seen ? 0 : sigmoid(acc)        (final logits)
#define BM 128
#define BN 128
#define BK 32

template <int EPI>
__global__ __launch_bounds__(256) void gemm_bt(
    const u16* __restrict__ A, const u16* __restrict__ Bmat,
    int M, int N, int K,
    float* __restrict__ out,
    const float* __restrict__ lm, const float* __restrict__ Vw,
    float* __restrict__ scores, const unsigned* __restrict__ seen) {
  __shared__ bf16x8 Asl[BM * BK / 8];   // 512 16B chunks, row-major [128][32]
  __shared__ bf16x8 Bsl[BN * BK / 8];
  const int tid = threadIdx.x;
  const int lane = tid & 63;
  const int wid = tid >> 6;
  const int wr = wid >> 1, wc = wid & 1;      // 2x2 wave grid, 64x64 per wave
  const int la = lane & 15, lb = lane >> 4;
  const int m0 = blockIdx.y * BM;
  const int n0 = blockIdx.x * BN;

  const int ktotal = K / BK;
  const int kper = ktotal / gridDim.z;
  const int kt0 = blockIdx.z * kper, kt1 = kt0 + kper;

  f32x4 acc[4][4];
  const f32x4 zero = {0.f, 0.f, 0.f, 0.f};
#pragma unroll
  for (int i = 0; i < 4; ++i)
#pragma unroll
    for (int j = 0; j < 4; ++j) acc[i][j] = zero;

  // staging: 512 chunks of 16B per tile; thread handles chunks tid and tid+256
  const int c0 = tid, c1 = tid + 256;
  const int r0 = c0 >> 2, e0 = (c0 & 3) * 8;
  const int r1 = c1 >> 2, e1 = (c1 & 3) * 8;
  // wave-uniform LDS bases (HW writes base + lane*16)
  bf16x8* ldsA0 = &Asl[wid * 64];
  bf16x8* ldsA1 = &Asl[256 + wid * 64];
  bf16x8* ldsB0 = &Bsl[wid * 64];
  bf16x8* ldsB1 = &Bsl[256 + wid * 64];
  // clamp B rows for the partial last n-tile (EPI2); harmless elsewhere
  int br0 = n0 + r0; if (br0 > N - 1) br0 = N - 1;
  int br1 = n0 + r1; if (br1 > N - 1) br1 = N - 1;

  for (int kt = kt0; kt < kt1; ++kt) {
    const int k0 = kt * BK;
    const u16* ga0 = A + (long)(m0 + r0) * K + k0 + e0;
    const u16* ga1 = A + (long)(m0 + r1) * K + k0 + e1;
    const u16* gb0 = Bmat + (long)br0 * K + k0 + e0;
    const u16* gb1 = Bmat + (long)br1 * K + k0 + e1;
    __builtin_amdgcn_global_load_lds((const __attribute__((address_space(1))) void*)ga0,
                                     (__attribute__((address_space(3))) void*)(void*)ldsA0, 16, 0, 0);
    __builtin_amdgcn_global_load_lds((const __attribute__((address_space(1))) void*)ga1,
                                     (__attribute__((address_space(3))) void*)(void*)ldsA1, 16, 0, 0);
    __builtin_amdgcn_global_load_lds((const __attribute__((address_space(1))) void*)gb0,
                                     (__attribute__((address_space(3))) void*)(void*)ldsB0, 16, 0, 0);
    __builtin_amdgcn_global_load_lds((const __attribute__((address_space(1))) void*)gb1,
                                     (__attribute__((address_space(3))) void*)(void*)ldsB1, 16, 0, 0);
    __syncthreads();   // compiler drains vmcnt before barrier

    bf16x8 af[4], bfr[4];
#pragma unroll
    for (int mi = 0; mi < 4; ++mi)
      af[mi] = Asl[(wr * 64 + mi * 16 + la) * 4 + lb];   // A[row][k-chunk lb]
#pragma unroll
    for (int ni = 0; ni < 4; ++ni)
      bfr[ni] = Bsl[(wc * 64 + ni * 16 + la) * 4 + lb];  // B[ncol][k-chunk lb]
#pragma unroll
    for (int mi = 0; mi < 4; ++mi)
#pragma unroll
      for (int ni = 0; ni < 4; ++ni)
        acc[mi][ni] = __builtin_amdgcn_mfma_f32_16x16x32_bf16(af[mi], bfr[ni], acc[mi][ni], 0, 0, 0);
    __syncthreads();
  }

  // C/D layout (verified): col = lane&15, row = (lane>>4)*4 + reg
  if constexpr (EPI == 0) {
#pragma unroll
    for (int mi = 0; mi < 4; ++mi)
#pragma unroll
      for (int i = 0; i < 4; ++i) {
        int r = m0 + wr * 64 + mi * 16 + lb * 4 + i;
#pragma unroll
        for (int ni = 0; ni < 4; ++ni) {
          int c = n0 + wc * 64 + ni * 16 + la;
          atomicAdd(&out[(long)r * N + c], acc[mi][ni][i]);
        }
      }
  }
  if constexpr (EPI == 1) {
#pragma unroll
    for (int mi = 0; mi < 4; ++mi)
#pragma unroll
      for (int i = 0; i < 4; ++i) {
        int r = m0 + wr * 64 + mi * 16 + lb * 4 + i;
        int bidx = r / Sdim;
        float p = 0.f;
#pragma unroll
        for (int ni = 0; ni < 4; ++ni) {
          int c = n0 + wc * 64 + ni * 16 + la;
          float t = tanhf(acc[mi][ni][i] + lm[bidx * Hdim + c]);
          p += Vw[c] * t;
        }
        p += __shfl_xor(p, 1);
        p += __shfl_xor(p, 2);
        p += __shfl_xor(p, 4);
        p += __shfl_xor(p, 8);
        if (la == 0) atomicAdd(&scores[r], p);
      }
  }
  if constexpr (EPI == 2) {
#pragma unroll
    for (int mi = 0; mi < 4; ++mi)
#pragma unroll
      for (int i = 0; i < 4; ++i) {
        int r = m0 + wr * 64 + mi * 16 + lb * 4 + i;
        long rb = (long)r * Ndim;
#pragma unroll
        for (int ni = 0; ni < 4; ++ni) {
          int c = n0 + wc * 64 + ni * 16 + la;
          if (c < Ndim) {
            unsigned wbits = seen[r * SEENW + (c >> 5)];
            float val = 0.f;
            if (!((wbits >> (c & 31)) & 1u))
              val = 1.f / (1.f + __expf(-acc[mi][ni][i]));
            out[rb + c] = val;
          }
        }
      }
  }
}

// ---------------- launcher ----------------
extern "C" void kernel_launch(void* const* d_in, const int* in_sizes, int n_in,
                              void* d_out, int out_size, void* d_ws, size_t ws_size,
                              hipStream_t stream) {
  (void)in_sizes; (void)n_in; (void)out_size; (void)ws_size;
  const float* all_memory  = (const float*)d_in[0];
  const float* last_memory = (const float*)d_in[1];
  const int*   item_seq    = (const int*)d_in[2];
  const unsigned char* mask = (const unsigned char*)d_in[3];
  const float* U_w = (const float*)d_in[4];
  const float* W_w = (const float*)d_in[5];
  const float* V_w = (const float*)d_in[6];
  const float* V_b = (const float*)d_in[7];
  const float* E_w = (const float*)d_in[8];
  float* out = (float*)d_out;

  char* w = (char*)d_ws;
  u16* wsE    = (u16*)w; w += (size_t)Ndim * Kdim2 * 2;         // 40.96 MB
  u16* wsA    = (u16*)w; w += (size_t)Bdim * Sdim * Hdim * 2;   // 26.2 MB
  u16* wsFeat = (u16*)w; w += (size_t)Bdim * Kdim2 * 2;         // 1 MB
  u16* wsLast = (u16*)w; w += (size_t)Hdim * Hdim * 2;          // 0.5 MB
  u16* wsW    = (u16*)w; w += (size_t)Hdim * Hdim * 2;
  u16* wsU    = (u16*)w; w += (size_t)Hdim * Hdim * 2;
  float* wsLm     = (float*)w; w += (size_t)Bdim * Hdim * 4;    // 1 MB
  float* wsScores = (float*)w; w += (size_t)Bdim * Sdim * 4;
  unsigned* wsSeen = (unsigned*)w; w += (size_t)Bdim * SEENW * 4;

  cast_kernel<<<2048, 256, 0, stream>>>(E_w, wsE, Ndim * Kdim2 / 4);
  cast_kernel<<<2048, 256, 0, stream>>>(all_memory, wsA, Bdim * Sdim * Hdim / 4);
  cast3_kernel<<<256, 256, 0, stream>>>(last_memory, wsLast, W_w, wsW, U_w, wsU);
  init_kernel<<<512, 256, 0, stream>>>(wsScores, wsLm, wsSeen, V_b);
  scatter_kernel<<<100, 256, 0, stream>>>(item_seq, wsSeen);

  // lm = last_memory @ W_w^T   (512x512x512, split-K=4, atomic accumulate)
  gemm_bt<0><<<dim3(Hdim / BN, Bdim / BM, 4), 256, 0, stream>>>(
      wsLast, wsW, Bdim, Hdim, Hdim, wsLm, nullptr, nullptr, nullptr, nullptr);
  // scores += sum_k V[k]*tanh(am + lm)   (25600x512x512)
  gemm_bt<1><<<dim3(Hdim / BN, Bdim * Sdim / BM, 1), 256, 0, stream>>>(
      wsA, wsU, Bdim * Sdim, Hdim, Hdim, nullptr, wsLm, V_w, wsScores, nullptr);
  softmax_ctx_kernel<<<Bdim, 256, 0, stream>>>(wsScores, mask, all_memory, last_memory, wsFeat);
  // out = sigmoid/mask( feat @ E_w^T )   (512x20000x1024)
  gemm_bt<2><<<dim3((Ndim + BN - 1) / BN, Bdim / BM, 1), 256, 0, stream>>>(
      wsFeat, wsE, Bdim, Ndim, Kdim2, out, nullptr, nullptr, nullptr, wsSeen);
}

// Round 2
// 158.877 us; speedup vs baseline: 1.1159x; 1.1159x over previous
//
#include <hip/hip_runtime.h>
#include <hip/hip_bf16.h>

#define Bdim 512
#define Sdim 50
#define Hdim 512
#define Ndim 20000
#define Kdim2 1024   // 2*H
#define SEENW 640    // u32 words per row for the seen-bitmask (20000 bits -> 625, pad 640)

typedef __bf16 bf16x8 __attribute__((ext_vector_type(8)));
typedef float f32x4 __attribute__((ext_vector_type(4)));
typedef unsigned short u16;

__device__ __forceinline__ u16 f2bf(float f) {
  unsigned u = __builtin_bit_cast(unsigned, f);
  u = (u + 0x7fffu + ((u >> 16) & 1u)) >> 16;   // RNE
  return (u16)u;
}
__device__ __forceinline__ float bf2f(u16 v) {
  unsigned u = ((unsigned)v) << 16;
  return __builtin_bit_cast(float, u);
}

// ---------------- merged cast (E_w then all_memory) ----------------
__global__ __launch_bounds__(256) void cast2_kernel(const float* __restrict__ a, u16* __restrict__ da, int n4a,
                                                    const float* __restrict__ b, u16* __restrict__ db, int n4b) {
  int stride = gridDim.x * blockDim.x;
  int ntot = n4a + n4b;
  for (int i = blockIdx.x * blockDim.x + threadIdx.x; i < ntot; i += stride) {
    const float4* src; ushort4* dst; int j;
    if (i < n4a) { src = reinterpret_cast<const float4*>(a); dst = reinterpret_cast<ushort4*>(da); j = i; }
    else         { src = reinterpret_cast<const float4*>(b); dst = reinterpret_cast<ushort4*>(db); j = i - n4a; }
    float4 v = src[j];
    ushort4 o;
    o.x = f2bf(v.x); o.y = f2bf(v.y); o.z = f2bf(v.z); o.w = f2bf(v.w);
    dst[j] = o;
  }
}

__global__ __launch_bounds__(256) void cast3_kernel(const float* __restrict__ a, u16* __restrict__ da,
                                                    const float* __restrict__ b, u16* __restrict__ db,
                                                    const float* __restrict__ c, u16* __restrict__ dc) {
  int i = blockIdx.x * blockDim.x + threadIdx.x;   // 65536 threads, one float4 each
  float4 v; ushort4 o;
  v = reinterpret_cast<const float4*>(a)[i];
  o.x = f2bf(v.x); o.y = f2bf(v.y); o.z = f2bf(v.z); o.w = f2bf(v.w);
  reinterpret_cast<ushort4*>(da)[i] = o;
  v = reinterpret_cast<const float4*>(b)[i];
  o.x = f2bf(v.x); o.y = f2bf(v.y); o.z = f2bf(v.z); o.w = f2bf(v.w);
  reinterpret_cast<ushort4*>(db)[i] = o;
  v = reinterpret_cast<const float4*>(c)[i];
  o.x = f2bf(v.x); o.y = f2bf(v.y); o.z = f2bf(v.z); o.w = f2bf(v.w);
  reinterpret_cast<ushort4*>(dc)[i] = o;
}

// ---------------- init (scores=0, lm=0, seen=0) ----------------
// scores/lm are atomic-accumulated and seen is atomicOr'd -> must be zeroed
// EVERY call (graph replays don't re-poison). V_b dropped: softmax is
// shift-invariant, a constant bias on all scores of a row cancels.
__global__ __launch_bounds__(256) void init_kernel(float* __restrict__ scores,
                                                   float* __restrict__ lm,
                                                   unsigned* __restrict__ seen) {
  int stride = gridDim.x * blockDim.x;
  int t = blockIdx.x * blockDim.x + threadIdx.x;
  for (int i = t; i < Bdim * Sdim; i += stride) scores[i] = 0.f;
  for (int i = t; i < Bdim * Hdim; i += stride) lm[i] = 0.f;
  for (int i = t; i < Bdim * SEENW; i += stride) seen[i] = 0u;
}

// ---------------- seen-item scatter ----------------
__global__ __launch_bounds__(256) void scatter_kernel(const int* __restrict__ iseq,
                                                      unsigned* __restrict__ seen) {
  int i = blockIdx.x * blockDim.x + threadIdx.x;
  if (i < Bdim * Sdim) {
    int b = i / Sdim;
    int it = iseq[i];
    if (it > 0) atomicOr(&seen[b * SEENW + (it >> 5)], 1u << (it & 31));
  }
}

// ---------------- softmax over S + context readout -> feat (bf16) ----------------
// reads the bf16 copy of all_memory (half the traffic of fp32)
__global__ __launch_bounds__(256) void softmax_ctx_kernel(
    const float* __restrict__ scores, const unsigned char* __restrict__ mask,
    const u16* __restrict__ amB, const float* __restrict__ last_memory,
    u16* __restrict__ feat) {
  int b = blockIdx.x;
  __shared__ float alpha[Sdim];
  int tid = threadIdx.x;
  if (tid < 64) {
    float s = -1e30f;
    if (tid < Sdim) {
      s = scores[b * Sdim + tid];
      if (mask[b * Sdim + tid]) s = -1e9f;   // mask is all-false in this problem
    }
    float m = s;
#pragma unroll
    for (int off = 32; off; off >>= 1) m = fmaxf(m, __shfl_xor(m, off));
    float e = (tid < Sdim) ? __expf(s - m) : 0.f;
    float sum = e;
#pragma unroll
    for (int off = 32; off; off >>= 1) sum += __shfl_xor(sum, off);
    if (tid < Sdim) alpha[tid] = e / sum;
  }
  __syncthreads();
  for (int h = tid; h < Hdim; h += 256) {
    const u16* amp = amB + ((long)b * Sdim) * Hdim + h;
    float c = 0.f;
#pragma unroll 5
    for (int s = 0; s < Sdim; ++s) c += alpha[s] * bf2f(amp[(long)s * Hdim]);
    feat[b * Kdim2 + h] = f2bf(c);
    feat[b * Kdim2 + Hdim + h] = f2bf(last_memory[b * Hdim + h]);
  }
}

// ---------------- MFMA GEMM, B-transposed layout (A: MxK, Bmat: NxK, both bf16) ----
// Double-buffered LDS, T3 minimum 2-phase schedule: issue next tile's
// global_load_lds BEFORE computing the current tile; single barrier per K-step.
// EPI 0: atomicAdd f32 into out (M x N), supports split-K via gridDim.z
// EPI 1: scores[r] += sum_c V[c]*tanh(acc + lm[b,c])   (additive-attention scores)
// EPI 2: out[r*Ndim+c] = seen ? 0 : sigmoid(acc)        (final logits)
#define BM 128
#define BN 128
#define BK 32

template <int EPI>
__global__ __launch_bounds__(256) void gemm_bt(
    const u16* __restrict__ A, const u16* __restrict__ Bmat,
    int M, int N, int K,
    float* __restrict__ out,
    const float* __restrict__ lm, const float* __restrict__ Vw,
    float* __restrict__ scores, const unsigned* __restrict__ seen) {
  __shared__ bf16x8 Asl[2][BM * BK / 8];   // 2 x 512 16B chunks, row-major [128][32]
  __shared__ bf16x8 Bsl[2][BN * BK / 8];
  const int tid = threadIdx.x;
  const int lane = tid & 63;
  const int wid = tid >> 6;
  const int wr = wid >> 1, wc = wid & 1;      // 2x2 wave grid, 64x64 per wave
  const int la = lane & 15, lb = lane >> 4;
  const int m0 = blockIdx.y * BM;
  const int n0 = blockIdx.x * BN;

  const int ktotal = K / BK;
  const int kper = ktotal / gridDim.z;
  const int kt0 = blockIdx.z * kper, kt1 = kt0 + kper;

  f32x4 acc[4][4];
  const f32x4 zero = {0.f, 0.f, 0.f, 0.f};
#pragma unroll
  for (int i = 0; i < 4; ++i)
#pragma unroll
    for (int j = 0; j < 4; ++j) acc[i][j] = zero;

  // staging: 512 chunks of 16B per tile; thread handles chunks tid and tid+256
  const int c1 = tid + 256;
  const int r0 = tid >> 2, e0 = (tid & 3) * 8;
  const int r1 = c1 >> 2, e1 = (c1 & 3) * 8;
  // clamp B rows for the partial last n-tile (EPI2); harmless elsewhere
  int br0 = n0 + r0; if (br0 > N - 1) br0 = N - 1;
  int br1 = n0 + r1; if (br1 > N - 1) br1 = N - 1;
  const u16* gA0 = A + (long)(m0 + r0) * K + e0;
  const u16* gA1 = A + (long)(m0 + r1) * K + e1;
  const u16* gB0 = Bmat + (long)br0 * K + e0;
  const u16* gB1 = Bmat + (long)br1 * K + e1;

  auto STAGE = [&](int buf, int kt) {
    const int k0 = kt * BK;
    __builtin_amdgcn_global_load_lds((const __attribute__((address_space(1))) void*)(gA0 + k0),
                                     (__attribute__((address_space(3))) void*)(void*)&Asl[buf][wid * 64], 16, 0, 0);
    __builtin_amdgcn_global_load_lds((const __attribute__((address_space(1))) void*)(gA1 + k0),
                                     (__attribute__((address_space(3))) void*)(void*)&Asl[buf][256 + wid * 64], 16, 0, 0);
    __builtin_amdgcn_global_load_lds((const __attribute__((address_space(1))) void*)(gB0 + k0),
                                     (__attribute__((address_space(3))) void*)(void*)&Bsl[buf][wid * 64], 16, 0, 0);
    __builtin_amdgcn_global_load_lds((const __attribute__((address_space(1))) void*)(gB1 + k0),
                                     (__attribute__((address_space(3))) void*)(void*)&Bsl[buf][256 + wid * 64], 16, 0, 0);
  };

  STAGE(0, kt0);
  __syncthreads();          // drain vmcnt(0) + barrier: buf0 ready
  int cur = 0;
  for (int kt = kt0; kt < kt1; ++kt) {
    if (kt + 1 < kt1) STAGE(cur ^ 1, kt + 1);   // issue next tile early

    bf16x8 af[4], bfr[4];
#pragma unroll
    for (int mi = 0; mi < 4; ++mi)
      af[mi] = Asl[cur][(wr * 64 + mi * 16 + la) * 4 + lb];   // A[row][k-chunk lb]
#pragma unroll
    for (int ni = 0; ni < 4; ++ni)
      bfr[ni] = Bsl[cur][(wc * 64 + ni * 16 + la) * 4 + lb];  // B[ncol][k-chunk lb]
#pragma unroll
    for (int mi = 0; mi < 4; ++mi)
#pragma unroll
      for (int ni = 0; ni < 4; ++ni)
        acc[mi][ni] = __builtin_amdgcn_mfma_f32_16x16x32_bf16(af[mi], bfr[ni], acc[mi][ni], 0, 0, 0);
    __syncthreads();        // one barrier per K-step; drains the new stage too
    cur ^= 1;
  }

  // C/D layout (verified): col = lane&15, row = (lane>>4)*4 + reg
  if constexpr (EPI == 0) {
#pragma unroll
    for (int mi = 0; mi < 4; ++mi)
#pragma unroll
      for (int i = 0; i < 4; ++i) {
        int r = m0 + wr * 64 + mi * 16 + lb * 4 + i;
#pragma unroll
        for (int ni = 0; ni < 4; ++ni) {
          int c = n0 + wc * 64 + ni * 16 + la;
          atomicAdd(&out[(long)r * N + c], acc[mi][ni][i]);
        }
      }
  }
  if constexpr (EPI == 1) {
#pragma unroll
    for (int mi = 0; mi < 4; ++mi)
#pragma unroll
      for (int i = 0; i < 4; ++i) {
        int r = m0 + wr * 64 + mi * 16 + lb * 4 + i;
        int bidx = r / Sdim;
        float p = 0.f;
#pragma unroll
        for (int ni = 0; ni < 4; ++ni) {
          int c = n0 + wc * 64 + ni * 16 + la;
          float x = acc[mi][ni][i] + lm[bidx * Hdim + c];
          x = fminf(fmaxf(x, -9.f), 9.f);           // tanh saturates; avoid inf/inf
          float e = __expf(2.f * x);
          p += Vw[c] * ((e - 1.f) / (e + 1.f));
        }
        p += __shfl_xor(p, 1);
        p += __shfl_xor(p, 2);
        p += __shfl_xor(p, 4);
        p += __shfl_xor(p, 8);
        if (la == 0) atomicAdd(&scores[r], p);
      }
  }
  if constexpr (EPI == 2) {
#pragma unroll
    for (int mi = 0; mi < 4; ++mi)
#pragma unroll
      for (int i = 0; i < 4; ++i) {
        int r = m0 + wr * 64 + mi * 16 + lb * 4 + i;
        long rb = (long)r * Ndim;
#pragma unroll
        for (int ni = 0; ni < 4; ++ni) {
          int c = n0 + wc * 64 + ni * 16 + la;
          if (c < Ndim) {
            unsigned wbits = seen[r * SEENW + (c >> 5)];
            float val = 0.f;
            if (!((wbits >> (c & 31)) & 1u))
              val = 1.f / (1.f + __expf(-acc[mi][ni][i]));
            out[rb + c] = val;
          }
        }
      }
  }
}

// ---------------- launcher ----------------
extern "C" void kernel_launch(void* const* d_in, const int* in_sizes, int n_in,
                              void* d_out, int out_size, void* d_ws, size_t ws_size,
                              hipStream_t stream) {
  (void)in_sizes; (void)n_in; (void)out_size; (void)ws_size;
  const float* all_memory  = (const float*)d_in[0];
  const float* last_memory = (const float*)d_in[1];
  const int*   item_seq    = (const int*)d_in[2];
  const unsigned char* mask = (const unsigned char*)d_in[3];
  const float* U_w = (const float*)d_in[4];
  const float* W_w = (const float*)d_in[5];
  const float* V_w = (const float*)d_in[6];
  const float* E_w = (const float*)d_in[8];
  float* out = (float*)d_out;

  char* w = (char*)d_ws;
  u16* wsE    = (u16*)w; w += (size_t)Ndim * Kdim2 * 2;         // 40.96 MB
  u16* wsA    = (u16*)w; w += (size_t)Bdim * Sdim * Hdim * 2;   // 26.2 MB
  u16* wsFeat = (u16*)w; w += (size_t)Bdim * Kdim2 * 2;         // 1 MB
  u16* wsLast = (u16*)w; w += (size_t)Hdim * Hdim * 2;          // 0.5 MB
  u16* wsW    = (u16*)w; w += (size_t)Hdim * Hdim * 2;
  u16* wsU    = (u16*)w; w += (size_t)Hdim * Hdim * 2;
  float* wsLm     = (float*)w; w += (size_t)Bdim * Hdim * 4;    // 1 MB
  float* wsScores = (float*)w; w += (size_t)Bdim * Sdim * 4;
  unsigned* wsSeen = (unsigned*)w; w += (size_t)Bdim * SEENW * 4;

  cast2_kernel<<<4096, 256, 0, stream>>>(E_w, wsE, Ndim * Kdim2 / 4,
                                         all_memory, wsA, Bdim * Sdim * Hdim / 4);
  cast3_kernel<<<256, 256, 0, stream>>>(last_memory, wsLast, W_w, wsW, U_w, wsU);
  init_kernel<<<512, 256, 0, stream>>>(wsScores, wsLm, wsSeen);
  scatter_kernel<<<100, 256, 0, stream>>>(item_seq, wsSeen);

  // lm = last_memory @ W_w^T   (512x512x512, split-K=4, atomic accumulate)
  gemm_bt<0><<<dim3(Hdim / BN, Bdim / BM, 4), 256, 0, stream>>>(
      wsLast, wsW, Bdim, Hdim, Hdim, wsLm, nullptr, nullptr, nullptr, nullptr);
  // scores += sum_k V[k]*tanh(am + lm)   (25600x512x512)
  gemm_bt<1><<<dim3(Hdim / BN, Bdim * Sdim / BM, 1), 256, 0, stream>>>(
      wsA, wsU, Bdim * Sdim, Hdim, Hdim, nullptr, wsLm, V_w, wsScores, nullptr);
  softmax_ctx_kernel<<<Bdim, 256, 0, stream>>>(wsScores, mask, wsA, last_memory, wsFeat);
  // out = sigmoid/mask( feat @ E_w^T )   (512x20000x1024)
  gemm_bt<2><<<dim3((Ndim + BN - 1) / BN, Bdim / BM, 1), 256, 0, stream>>>(
      wsFeat, wsE, Bdim, Ndim, Kdim2, out, nullptr, nullptr, nullptr, wsSeen);
}